// Round 19
// baseline (3407.502 us; speedup 1.0000x reference)
//
#include <hip/hip_runtime.h>
#include <hip/hip_bf16.h>
#include <cstdint>

#define BATCH 8
#define LATC 256
#define NCODE 1024
#define NLVL 4

typedef __attribute__((ext_vector_type(8))) short bf16x8v;
typedef __attribute__((ext_vector_type(4))) float f32x4v;

__device__ __forceinline__ unsigned short f2b(float f) {
  __hip_bfloat16 h = __float2bfloat16(f);
  return *reinterpret_cast<unsigned short*>(&h);
}

// async global->LDS 16B: LDS base = readfirstlane(lane0 offset), HW writes base + lane*16
__device__ __forceinline__ void gl_lds16(const void* gptr, unsigned lds_byte_off) {
  unsigned m0v = __builtin_amdgcn_readfirstlane(lds_byte_off);
  asm volatile("s_mov_b32 m0, %0\n"
               "global_load_lds_dwordx4 %1, off\n" ::"s"(m0v), "v"(gptr)
               : "memory");
}

// ================= encoder conv k4 s2 p1 v2: 8px x 8co per thread (round-14, verified) ========
template <int CIN, int COUT, int HIN, int CI_CHUNK, int CO_TILE, int CI_SPLIT>
__global__ __launch_bounds__(256) void conv_enc2(
    const float* __restrict__ in, const float* __restrict__ w,
    const float* __restrict__ bias, float* __restrict__ out) {
  constexpr int WIN = HIN;
  constexpr int HOUT = HIN / 2, WOUT = WIN / 2;
  constexpr int PT1 = HOUT / 16;
  constexpr int NEL = CI_CHUNK * 34 * 34;
  constexpr int WUNITS = CI_CHUNK * CO_TILE * 4;
  constexpr int CIPS = CIN / CI_SPLIT;

  __shared__ float T[CI_CHUNK][34][40];
  __shared__ float4 Wsh[CI_CHUNK][CO_TILE][4];

  const int tid = threadIdx.x;
  const int lane = tid & 63;
  const int wv = __builtin_amdgcn_readfirstlane(tid >> 6);
  const int cog = lane >> 5;
  const int pxi = lane & 31;
  const int m = pxi >> 2;
  const int ox4 = pxi & 3;
  const int co_loc0 = (wv * 2 + cog) * 8;

  const int bx = blockIdx.x;
  const int n = bx / (PT1 * PT1);
  const int pt = bx % (PT1 * PT1);
  const int oh0 = (pt / PT1) * 16, ow0 = (pt % PT1) * 16;
  const int hbase = 2 * oh0 - 1, wbase = 2 * ow0 - 1;
  const int co_blk = blockIdx.y * CO_TILE;
  const int split = (CI_SPLIT > 1) ? blockIdx.z : 0;
  const int ci_base = split * CIPS;

  float acc[2][4][2][4];
#pragma unroll
  for (int cl = 0; cl < 2; ++cl)
#pragma unroll
    for (int j = 0; j < 4; ++j) {
      float b = (CI_SPLIT == 1 || split == 0) ? bias[co_blk + co_loc0 + cl * 4 + j] : 0.f;
#pragma unroll
      for (int dy = 0; dy < 2; ++dy)
#pragma unroll
        for (int dx = 0; dx < 4; ++dx) acc[cl][j][dy][dx] = b;
    }

  for (int ch = ci_base; ch < ci_base + CIPS; ch += CI_CHUNK) {
    for (int u = tid; u < NEL; u += 256) {
      int cir = u / 1156;
      int rem = u - cir * 1156;
      int r = rem / 34, c = rem - r * 34;
      int hi = hbase + r, wi = wbase + c;
      float v = 0.f;
      if ((unsigned)hi < (unsigned)HIN && (unsigned)wi < (unsigned)WIN)
        v = in[((long long)(n * CIN + ch + cir) * HIN + hi) * WIN + wi];
      T[cir][r][(((r >> 2) & 1) << 2) + c] = v;
    }
    for (int u = tid; u < WUNITS; u += 256) {
      int k4 = u & 3;
      int rem = u >> 2;
      int co = rem % CO_TILE, ci = rem / CO_TILE;
      Wsh[ci][co][k4] =
          *(const float4*)&w[((long long)(co_blk + co) * CIN + ch + ci) * 16 + k4 * 4];
    }
    __syncthreads();
#pragma unroll
    for (int cir = 0; cir < CI_CHUNK; ++cir) {
      float xv[6][10];
#pragma unroll
      for (int roff = 0; roff < 6; ++roff) {
        int row = 4 * m + roff;
        const float* base = &T[cir][row][(((row >> 2) & 1) << 2) + 8 * ox4];
        float4 qa = *(const float4*)base;
        float4 qb = *(const float4*)(base + 4);
        float4 qc = *(const float4*)(base + 8);
        xv[roff][0] = qa.x; xv[roff][1] = qa.y; xv[roff][2] = qa.z; xv[roff][3] = qa.w;
        xv[roff][4] = qb.x; xv[roff][5] = qb.y; xv[roff][6] = qb.z; xv[roff][7] = qb.w;
        xv[roff][8] = qc.x; xv[roff][9] = qc.y;
      }
#pragma unroll
      for (int cl = 0; cl < 2; ++cl)
#pragma unroll
        for (int j = 0; j < 4; ++j) {
          int co_l = co_loc0 + cl * 4 + j;
#pragma unroll
          for (int kh = 0; kh < 4; ++kh) {
            float4 wq = Wsh[cir][co_l][kh];
            float wt0 = wq.x, wt1 = wq.y, wt2 = wq.z, wt3 = wq.w;
#pragma unroll
            for (int dy = 0; dy < 2; ++dy) {
              int r = 2 * dy + kh;
#pragma unroll
              for (int dx = 0; dx < 4; ++dx) {
                acc[cl][j][dy][dx] = fmaf(xv[r][2 * dx + 0], wt0, acc[cl][j][dy][dx]);
                acc[cl][j][dy][dx] = fmaf(xv[r][2 * dx + 1], wt1, acc[cl][j][dy][dx]);
                acc[cl][j][dy][dx] = fmaf(xv[r][2 * dx + 2], wt2, acc[cl][j][dy][dx]);
                acc[cl][j][dy][dx] = fmaf(xv[r][2 * dx + 3], wt3, acc[cl][j][dy][dx]);
              }
            }
          }
        }
    }
    __syncthreads();
  }
  const long long psz = (long long)BATCH * COUT * HOUT * WOUT;
  float* __restrict__ ob_ptr = out + (CI_SPLIT > 1 ? (long long)split * psz : 0LL);
#pragma unroll
  for (int cl = 0; cl < 2; ++cl)
#pragma unroll
    for (int j = 0; j < 4; ++j) {
      int co = co_blk + co_loc0 + cl * 4 + j;
#pragma unroll
      for (int dy = 0; dy < 2; ++dy) {
        int oh = oh0 + 2 * m + dy, ow = ow0 + 4 * ox4;
        float4 v;
#pragma unroll
        for (int dx = 0; dx < 4; ++dx) {
          float t = acc[cl][j][dy][dx];
          if (CI_SPLIT == 1) t = fmaxf(t, 0.f);
          ((float*)&v)[dx] = t;
        }
        *reinterpret_cast<float4*>(
            &ob_ptr[((long long)(n * COUT + co) * HOUT + oh) * WOUT + ow]) = v;
      }
    }
}

// ================= encoder conv v3: LDS double-buffer, ONE barrier per chunk ==================
// Same thread mapping / staged values / FMA chains as conv_enc2 (z bit-identical).
// T/Wsh x2 (76.3 KB, still 2 blocks/CU): stage(next) overlaps other waves' compute(cur);
// single barrier per chunk removes the staging-drain stall (measured ~33% idle).
template <int CIN, int COUT, int HIN, int CI_CHUNK, int CO_TILE, int CI_SPLIT>
__global__ __launch_bounds__(256) void conv_enc3(
    const float* __restrict__ in, const float* __restrict__ w,
    const float* __restrict__ bias, float* __restrict__ out) {
  constexpr int WIN = HIN;
  constexpr int HOUT = HIN / 2, WOUT = WIN / 2;
  constexpr int PT1 = HOUT / 16;
  constexpr int NEL = CI_CHUNK * 34 * 34;
  constexpr int WUNITS = CI_CHUNK * CO_TILE * 4;
  constexpr int CIPS = CIN / CI_SPLIT;
  constexpr int NCHK = CIPS / CI_CHUNK;

  __shared__ float T[2][CI_CHUNK][34][40];
  __shared__ float4 Wsh[2][CI_CHUNK][CO_TILE][4];

  const int tid = threadIdx.x;
  const int lane = tid & 63;
  const int wv = __builtin_amdgcn_readfirstlane(tid >> 6);
  const int cog = lane >> 5;
  const int pxi = lane & 31;
  const int m = pxi >> 2;
  const int ox4 = pxi & 3;
  const int co_loc0 = (wv * 2 + cog) * 8;

  const int bx = blockIdx.x;
  const int n = bx / (PT1 * PT1);
  const int pt = bx % (PT1 * PT1);
  const int oh0 = (pt / PT1) * 16, ow0 = (pt % PT1) * 16;
  const int hbase = 2 * oh0 - 1, wbase = 2 * ow0 - 1;
  const int co_blk = blockIdx.y * CO_TILE;
  const int split = (CI_SPLIT > 1) ? blockIdx.z : 0;
  const int ci_base = split * CIPS;

  float acc[2][4][2][4];
#pragma unroll
  for (int cl = 0; cl < 2; ++cl)
#pragma unroll
    for (int j = 0; j < 4; ++j) {
      float b = (CI_SPLIT == 1 || split == 0) ? bias[co_blk + co_loc0 + cl * 4 + j] : 0.f;
#pragma unroll
      for (int dy = 0; dy < 2; ++dy)
#pragma unroll
        for (int dx = 0; dx < 4; ++dx) acc[cl][j][dy][dx] = b;
    }

  auto stage = [&](int buf, int ch) {
    for (int u = tid; u < NEL; u += 256) {
      int cir = u / 1156;
      int rem = u - cir * 1156;
      int r = rem / 34, c = rem - r * 34;
      int hi = hbase + r, wi = wbase + c;
      float v = 0.f;
      if ((unsigned)hi < (unsigned)HIN && (unsigned)wi < (unsigned)WIN)
        v = in[((long long)(n * CIN + ch + cir) * HIN + hi) * WIN + wi];
      T[buf][cir][r][(((r >> 2) & 1) << 2) + c] = v;
    }
    for (int u = tid; u < WUNITS; u += 256) {
      int k4 = u & 3;
      int rem = u >> 2;
      int co = rem % CO_TILE, ci = rem / CO_TILE;
      Wsh[buf][ci][co][k4] =
          *(const float4*)&w[((long long)(co_blk + co) * CIN + ch + ci) * 16 + k4 * 4];
    }
  };

  auto compute = [&](int buf) {
#pragma unroll
    for (int cir = 0; cir < CI_CHUNK; ++cir) {
      float xv[6][10];
#pragma unroll
      for (int roff = 0; roff < 6; ++roff) {
        int row = 4 * m + roff;
        const float* base = &T[buf][cir][row][(((row >> 2) & 1) << 2) + 8 * ox4];
        float4 qa = *(const float4*)base;
        float4 qb = *(const float4*)(base + 4);
        float4 qc = *(const float4*)(base + 8);
        xv[roff][0] = qa.x; xv[roff][1] = qa.y; xv[roff][2] = qa.z; xv[roff][3] = qa.w;
        xv[roff][4] = qb.x; xv[roff][5] = qb.y; xv[roff][6] = qb.z; xv[roff][7] = qb.w;
        xv[roff][8] = qc.x; xv[roff][9] = qc.y;
      }
#pragma unroll
      for (int cl = 0; cl < 2; ++cl)
#pragma unroll
        for (int j = 0; j < 4; ++j) {
          int co_l = co_loc0 + cl * 4 + j;
#pragma unroll
          for (int kh = 0; kh < 4; ++kh) {
            float4 wq = Wsh[buf][cir][co_l][kh];
            float wt0 = wq.x, wt1 = wq.y, wt2 = wq.z, wt3 = wq.w;
#pragma unroll
            for (int dy = 0; dy < 2; ++dy) {
              int r = 2 * dy + kh;
#pragma unroll
              for (int dx = 0; dx < 4; ++dx) {
                acc[cl][j][dy][dx] = fmaf(xv[r][2 * dx + 0], wt0, acc[cl][j][dy][dx]);
                acc[cl][j][dy][dx] = fmaf(xv[r][2 * dx + 1], wt1, acc[cl][j][dy][dx]);
                acc[cl][j][dy][dx] = fmaf(xv[r][2 * dx + 2], wt2, acc[cl][j][dy][dx]);
                acc[cl][j][dy][dx] = fmaf(xv[r][2 * dx + 3], wt3, acc[cl][j][dy][dx]);
              }
            }
          }
        }
    }
  };

  stage(0, ci_base);
  __syncthreads();
  int cur = 0;
  for (int chk = 0; chk < NCHK; ++chk) {
    if (chk + 1 < NCHK) stage(cur ^ 1, ci_base + (chk + 1) * CI_CHUNK);
    compute(cur);
    __syncthreads();   // stage(cur^1) done for all; compute(cur) reads done before overwrite
    cur ^= 1;
  }

  const long long psz = (long long)BATCH * COUT * HOUT * WOUT;
  float* __restrict__ ob_ptr = out + (CI_SPLIT > 1 ? (long long)split * psz : 0LL);
#pragma unroll
  for (int cl = 0; cl < 2; ++cl)
#pragma unroll
    for (int j = 0; j < 4; ++j) {
      int co = co_blk + co_loc0 + cl * 4 + j;
#pragma unroll
      for (int dy = 0; dy < 2; ++dy) {
        int oh = oh0 + 2 * m + dy, ow = ow0 + 4 * ox4;
        float4 v;
#pragma unroll
        for (int dx = 0; dx < 4; ++dx) {
          float t = acc[cl][j][dy][dx];
          if (CI_SPLIT == 1) t = fmaxf(t, 0.f);
          ((float*)&v)[dx] = t;
        }
        *reinterpret_cast<float4*>(
            &ob_ptr[((long long)(n * COUT + co) * HOUT + oh) * WOUT + ow]) = v;
      }
    }
}

// ---------------- fuse: out = (relu?) sum of S partials ----------------
template <int S, bool RELU>
__global__ __launch_bounds__(256) void fuse_sum(const float* __restrict__ p,
                                                float* __restrict__ out, long long n4) {
  long long i = (long long)blockIdx.x * 256 + threadIdx.x;
  long long stride = (long long)gridDim.x * 256;
  long long N = n4 * 4;
  for (; i < n4; i += stride) {
    float4 a = *(const float4*)&p[i * 4];
#pragma unroll
    for (int s = 1; s < S; ++s) {
      float4 b = *(const float4*)&p[(long long)s * N + i * 4];
      a.x += b.x; a.y += b.y; a.z += b.z; a.w += b.w;
    }
    if (RELU) {
      a.x = fmaxf(a.x, 0.f); a.y = fmaxf(a.y, 0.f);
      a.z = fmaxf(a.z, 0.f); a.w = fmaxf(a.w, 0.f);
    }
    *(float4*)&out[i * 4] = a;
  }
}

// ---------------- weight transpose for 1x1 conv ----------------
__global__ __launch_bounds__(256) void wtrans(const float* __restrict__ pw,
                                              float* __restrict__ pwT) {
  int gid = blockIdx.x * 256 + threadIdx.x;
  if (gid >= 512 * 256) return;
  int ci = gid >> 8, co = gid & 255;
  pwT[gid] = pw[co * 512 + ci];
}

// ---------------- 1x1 conv as GEMM, ci-split (z) ----------------
template <int CI_SPLIT>
__global__ __launch_bounds__(256) void conv1x1_v2(
    const float* __restrict__ in, const float* __restrict__ pwT,
    const float* __restrict__ bias, float* __restrict__ out) {
  constexpr int CIPS = 512 / CI_SPLIT;
  __shared__ float Tx[16][128];
  const int tid = threadIdx.x;
  const int lane = tid & 63;
  const int wv = __builtin_amdgcn_readfirstlane(tid >> 6);
  const int p0 = lane * 2;
  const int bx = blockIdx.x;
  const int n = bx >> 3, pxb = bx & 7;
  const int px_base = pxb * 128;
  const int co_base = blockIdx.y * 64 + wv * 16;
  const int split = (CI_SPLIT > 1) ? blockIdx.z : 0;
  const int ci0 = split * CIPS;

  float acc[4][4][2];
#pragma unroll
  for (int cl = 0; cl < 4; ++cl)
#pragma unroll
    for (int j = 0; j < 4; ++j) {
      float b = (CI_SPLIT == 1 || split == 0) ? bias[co_base + cl * 4 + j] : 0.f;
      acc[cl][j][0] = b; acc[cl][j][1] = b;
    }

  for (int ch = ci0; ch < ci0 + CIPS; ch += 16) {
    for (int u = tid; u < 2048; u += 256) {
      int cir = u >> 7, p = u & 127;
      Tx[cir][p] = in[(long long)(n * 512 + ch + cir) * 1024 + px_base + p];
    }
    __syncthreads();
#pragma unroll
    for (int cir = 0; cir < 16; ++cir) {
      float2 xv = *reinterpret_cast<const float2*>(&Tx[cir][p0]);
#pragma unroll
      for (int cl = 0; cl < 4; ++cl) {
        const float* __restrict__ wp = pwT + (ch + cir) * 256 + co_base + cl * 4;
#pragma unroll
        for (int j = 0; j < 4; ++j) {
          float wt = wp[j];
          acc[cl][j][0] = fmaf(xv.x, wt, acc[cl][j][0]);
          acc[cl][j][1] = fmaf(xv.y, wt, acc[cl][j][1]);
        }
      }
    }
    __syncthreads();
  }
  const long long psz = (long long)BATCH * 256 * 1024;
  float* __restrict__ ob = out + (CI_SPLIT > 1 ? (long long)split * psz : 0LL);
#pragma unroll
  for (int cl = 0; cl < 4; ++cl)
#pragma unroll
    for (int j = 0; j < 4; ++j) {
      int co = co_base + cl * 4 + j;
      *reinterpret_cast<float2*>(&ob[(long long)(n * 256 + co) * 1024 + px_base + p0]) =
          make_float2(acc[cl][j][0], acc[cl][j][1]);
    }
}

// ---------------- per-code squared norms ----------------
__global__ __launch_bounds__(256) void emb_norms(
    const float* __restrict__ emb, float* __restrict__ en) {
  int k = blockIdx.x * blockDim.x + threadIdx.x;
  if (k >= NLVL * NCODE) return;
  const float* __restrict__ e = emb + (long long)k * LATC;
  float s = 0.f;
  for (int c = 0; c < LATC; ++c) s = fmaf(e[c], e[c], s);
  en[k] = s;
}

// ================= residual quantization v6 (round-18, verified) ========
#define RQ_P 32
#define RQ_CT 64
#define RQ_RS 260

__global__ __launch_bounds__(512) void rq_kernel6(
    const float* __restrict__ z, const float* __restrict__ emb,
    const float* __restrict__ en, float* __restrict__ zq_out,
    float* __restrict__ resid_out, float* __restrict__ codes_out) {
  __shared__ float e_sh[RQ_CT * RQ_RS];
  __shared__ float r_sh[RQ_P * RQ_RS];
  __shared__ float sum_sh[RQ_P];
  __shared__ float red_d[2][RQ_P];
  __shared__ int red_i[2][RQ_P];
  __shared__ int code_sh[RQ_P];
  const int tid = threadIdx.x;
  const int blk = blockIdx.x;
  const int n = (blk * RQ_P) >> 10;
  const int hw0 = (blk * RQ_P) & 1023;
  const long long zb = ((long long)n * LATC) * 1024 + hw0;

  for (int it = 0; it < 16; ++it) {
    int u = it * 512 + tid;
    int c = u >> 5, pix = u & 31;
    float v = z[zb + (long long)c * 1024 + pix];
    r_sh[pix * RQ_RS + c] = v;
    resid_out[((long long)n * LATC + c) * 1024 + hw0 + pix] = v;
  }
  __syncthreads();

  const int code_l = tid & 31;
  const int pixoff = (tid >> 5) & 7;
  const int half = tid >> 8;
  const int upix = tid >> 4;
  const int ucg = tid & 15;

  for (int l = 0; l < NLVL; ++l) {
    {
      float s = 0.f;
#pragma unroll
      for (int it = 0; it < 4; ++it) {
        int c4 = ucg + it * 16;
        float4 r4 = *(const float4*)&r_sh[upix * RQ_RS + c4 * 4];
        s += r4.x * r4.x + r4.y * r4.y + r4.z * r4.z + r4.w * r4.w;
      }
      s += __shfl_xor(s, 1); s += __shfl_xor(s, 2);
      s += __shfl_xor(s, 4); s += __shfl_xor(s, 8);
      if (ucg == 0) sum_sh[upix] = s;
    }
    __syncthreads();
    const float* __restrict__ E = emb + (long long)l * NCODE * LATC;
    const float* __restrict__ enl = en + l * NCODE;
    float best[4]; int bidx[4];
#pragma unroll
    for (int g = 0; g < 4; ++g) { best[g] = 3.4e38f; bidx[g] = 0; }
    for (int tile = 0; tile < NCODE / RQ_CT; ++tile) {
      const float* __restrict__ Et = E + (long long)tile * RQ_CT * LATC;
      for (int it = 0; it < 32; ++it) {
        int u = it * 512 + tid;
        int cc = u >> 8, ch = u & 255;
        e_sh[cc * RQ_RS + ch] = Et[cc * LATC + ch];
      }
      __syncthreads();
      const int erow = half * 32 + code_l;
      float acc[4] = {0.f, 0.f, 0.f, 0.f};
      for (int c4 = 0; c4 < 64; ++c4) {
        float4 e4 = *(const float4*)&e_sh[erow * RQ_RS + c4 * 4];
#pragma unroll
        for (int g = 0; g < 4; ++g) {
          float4 r4 = *(const float4*)&r_sh[(g * 8 + pixoff) * RQ_RS + c4 * 4];
          acc[g] = fmaf(r4.x, e4.x, acc[g]);
          acc[g] = fmaf(r4.y, e4.y, acc[g]);
          acc[g] = fmaf(r4.z, e4.z, acc[g]);
          acc[g] = fmaf(r4.w, e4.w, acc[g]);
        }
      }
      int code = tile * RQ_CT + erow;
      float ek2 = enl[code];
#pragma unroll
      for (int g = 0; g < 4; ++g) {
        float d2 = (sum_sh[g * 8 + pixoff] - 2.f * acc[g]) + ek2;
        if (d2 < best[g]) { best[g] = d2; bidx[g] = code; }
      }
      __syncthreads();
    }
#pragma unroll
    for (int g = 0; g < 4; ++g) {
      float bd = best[g]; int bi = bidx[g];
#pragma unroll
      for (int m = 1; m < 32; m <<= 1) {
        float od = __shfl_xor(bd, m);
        int oi = __shfl_xor(bi, m);
        if (od < bd || (od == bd && oi < bi)) { bd = od; bi = oi; }
      }
      if (code_l == 0) {
        int pix = g * 8 + pixoff;
        red_d[half][pix] = bd; red_i[half][pix] = bi;
      }
    }
    __syncthreads();
    if (tid < RQ_P) {
      float d = red_d[0][tid]; int ix = red_i[0][tid];
      float od = red_d[1][tid]; int oi = red_i[1][tid];
      if (od < d || (od == d && oi < ix)) { d = od; ix = oi; }
      code_sh[tid] = ix;
      codes_out[(long long)(l * BATCH + n) * 1024 + hw0 + tid] = (float)ix;
    }
    __syncthreads();
    {
      int sel = code_sh[upix];
      const float* __restrict__ esel = E + (long long)sel * LATC;
#pragma unroll
      for (int it = 0; it < 4; ++it) {
        int c4 = ucg + it * 16;
        float4 r4 = *(const float4*)&r_sh[upix * RQ_RS + c4 * 4];
        float4 e4 = *(const float4*)&esel[c4 * 4];
        r4.x -= e4.x; r4.y -= e4.y; r4.z -= e4.z; r4.w -= e4.w;
        *(float4*)&r_sh[upix * RQ_RS + c4 * 4] = r4;
        if (l < NLVL - 1) {
          long long rb = ((long long)((l + 1) * BATCH + n) * LATC + c4 * 4) * 1024 + hw0 + upix;
          resid_out[rb] = r4.x;
          resid_out[rb + 1024] = r4.y;
          resid_out[rb + 2048] = r4.z;
          resid_out[rb + 3072] = r4.w;
        }
      }
    }
    __syncthreads();
  }
  for (int it = 0; it < 16; ++it) {
    int u = it * 512 + tid;
    int c = u >> 5, pix = u & 31;
    float zv = z[zb + (long long)c * 1024 + pix];
    zq_out[zb + (long long)c * 1024 + pix] = zv - r_sh[pix * RQ_RS + c];
  }
}

// ---------------- zq (NCHW f32) -> padded NHWC bf16 [8][34][34][256] ----------------
__global__ __launch_bounds__(256) void to_nhwc_s1(const float* __restrict__ zq,
                                                  unsigned short* __restrict__ o) {
  __shared__ float tsh[32][33];
  int bx = blockIdx.x;
  int ct = bx & 7, y = (bx >> 3) & 31, n = bx >> 8;
  int tid = threadIdx.x;
  int x = tid & 31, cl = tid >> 5;
#pragma unroll
  for (int it = 0; it < 4; ++it) {
    int ci = it * 8 + cl;
    tsh[ci][x] = zq[((long long)(n * 256 + ct * 32 + ci) * 32 + y) * 32 + x];
  }
  __syncthreads();
  int ci = tid & 31, xg = tid >> 5;
#pragma unroll
  for (int it = 0; it < 4; ++it) {
    int xw = it * 8 + xg;
    o[(((long long)n * 34 + y + 1) * 34 + xw + 1) * 256 + ct * 32 + ci] = f2b(tsh[ci][xw]);
  }
}

// ---------------- weight prep: HWIO f32 -> [4ph][CIN/32][4tap][COUT][32] bf16 ----------------
__global__ __launch_bounds__(256) void wprep_k(const float* __restrict__ w,
                                               unsigned short* __restrict__ o,
                                               int CINc, int COUTc) {
  long long total = 16LL * CINc * COUTc;
  long long gid = (long long)blockIdx.x * 256 + threadIdx.x;
  if (gid >= total) return;
  int ci32 = (int)(gid & 31); long long t = gid >> 5;
  int co = (int)(t % COUTc); t /= COUTc;
  int tap = (int)(t & 3); t >>= 2;
  int nch = CINc / 32;
  int ch = (int)(t % nch); int phase = (int)(t / nch);
  int py = phase >> 1, px = phase & 1;
  int ky = py + 2 * (tap >> 1), kx = px + 2 * (tap & 1);
  int ci = ch * 32 + ci32;
  float v = w[(((long long)ky * 4 + kx) * CINc + ci) * COUTc + co];
  o[gid] = f2b(v);
}

// ================= transposed conv k4 s2 MFMA v2: plane-layout LDS ================
template <int CIN, int COUT, int TH, int TW, int Hi, int Wi, bool OUT_NCHW>
__global__ __launch_bounds__(256) void convt2(
    const unsigned short* __restrict__ xin, const unsigned short* __restrict__ wprep,
    const float* __restrict__ bias, unsigned short* __restrict__ outp) {
  constexpr int TWP = TW + 2, ROWS = TH + 2;
  constexpr int Hp = Hi + 2, Wp = Wi + 2;
  constexpr int NCH = CIN / 32;
  constexpr int XUNITS = ROWS * TWP;
  constexpr int XPAD = ((XUNITS + 255) / 256) * 256;
  constexpr int WBASE = 4 * XPAD;
  __shared__ unsigned short lds[(4 * XPAD + 4 * 256) * 8];

  const int tid = threadIdx.x;
  const int wv = tid >> 6, lane = tid & 63;
  const int l15 = lane & 15, seg = lane >> 4;

  constexpr int SW = Wi / TW, SH = Hi / TH;
  const int bx = blockIdx.x;
  const int n = bx / (SH * SW);
  const int srem = bx % (SH * SW);
  const int i0 = (srem / SW) * TH, j0 = (srem % SW) * TW;
  const int cob0 = blockIdx.y * 64;
  const int phase = blockIdx.z;
  const int pyp = phase >> 1, pxp = phase & 1;

  const unsigned short* xsrc = xin + (long long)n * Hp * Wp * CIN;

  f32x4v acc[4][4];
  if (!OUT_NCHW) {
#pragma unroll
    for (int b = 0; b < 4; ++b) {
      float bv = bias[cob0 + b * 16 + l15];
      f32x4v v = {bv, bv, bv, bv};
#pragma unroll
      for (int a = 0; a < 4; ++a) acc[a][b] = v;
    }
  } else {
#pragma unroll
    for (int a = 0; a < 4; ++a) {
      f32x4v v;
#pragma unroll
      for (int q = 0; q < 4; ++q) v[q] = bias[cob0 + a * 16 + seg * 4 + q];
#pragma unroll
      for (int b = 0; b < 4; ++b) acc[a][b] = v;
    }
  }

  for (int ch = 0; ch < NCH; ++ch) {
    __syncthreads();
#pragma unroll
    for (int sg = 0; sg < 4; ++sg) {
#pragma unroll
      for (int it = 0; it < XPAD / 256; ++it) {
        int u = it * 256 + tid;
        int us = u < XUNITS ? u : XUNITS - 1;
        int row = us / TWP, col = us % TWP;
        const unsigned short* g =
            xsrc + ((long long)(i0 + row) * Wp + (j0 + col)) * CIN + ch * 32 + sg * 8;
        gl_lds16(g, (unsigned)(unsigned long long)(const void*)&lds[(sg * XPAD + u) * 8]);
      }
    }
    {
      const unsigned short* wb = wprep + ((long long)phase * NCH + ch) * 4 * COUT * 32;
      int tap = tid >> 6, co = tid & 63;
#pragma unroll
      for (int sg = 0; sg < 4; ++sg) {
        const unsigned short* g = wb + ((long long)tap * COUT + cob0 + co) * 32 + sg * 8;
        gl_lds16(g, (unsigned)(unsigned long long)(const void*)&lds[(WBASE + sg * 256 + tid) * 8]);
      }
    }
    asm volatile("s_waitcnt vmcnt(0)" ::: "memory");
    __syncthreads();
#pragma unroll
    for (int t = 0; t < 4; ++t) {
      int oy = (t >> 1) - 1 + pyp, ox = (t & 1) - 1 + pxp;
      bf16x8v xf[4], wf[4];
#pragma unroll
      for (int i = 0; i < 4; ++i) {
        int p = wv * 64 + i * 16 + l15;
        int r = p / TW, c = p % TW;
        int xrow = r + oy + 1, xcol = c + ox + 1;
        xf[i] = *(const bf16x8v*)&lds[(seg * XPAD + xrow * TWP + xcol) * 8];
        wf[i] = *(const bf16x8v*)&lds[(WBASE + seg * 256 + t * 64 + i * 16 + l15) * 8];
      }
#pragma unroll
      for (int a = 0; a < 4; ++a)
#pragma unroll
        for (int b = 0; b < 4; ++b) {
          if (OUT_NCHW)
            acc[a][b] = __builtin_amdgcn_mfma_f32_16x16x32_bf16(wf[a], xf[b], acc[a][b], 0, 0, 0);
          else
            acc[a][b] = __builtin_amdgcn_mfma_f32_16x16x32_bf16(xf[a], wf[b], acc[a][b], 0, 0, 0);
        }
    }
  }

  if (!OUT_NCHW) {
    constexpr int Wpo = 2 * Wi + 2;
    long long ob_n = (long long)n * (2 * Hi + 2) * Wpo * COUT;
#pragma unroll
    for (int a = 0; a < 4; ++a)
#pragma unroll
      for (int q = 0; q < 4; ++q) {
        int p = wv * 64 + a * 16 + seg * 4 + q;
        int r = p / TW, c = p % TW;
        int yo = 2 * (i0 + r) + pyp + 1, xo = 2 * (j0 + c) + pxp + 1;
        long long ob = ob_n + ((long long)yo * Wpo + xo) * COUT + cob0;
#pragma unroll
        for (int b = 0; b < 4; ++b) {
          float v = fmaxf(acc[a][b][q], 0.f);
          outp[ob + b * 16 + l15] = f2b(v);
        }
      }
  } else {
    constexpr int Ho = 2 * Hi, Wo = 2 * Wi;
#pragma unroll
    for (int a = 0; a < 4; ++a)
#pragma unroll
      for (int q = 0; q < 4; ++q) {
        int co = cob0 + a * 16 + seg * 4 + q;
#pragma unroll
        for (int b = 0; b < 4; ++b) {
          int p = wv * 64 + b * 16 + l15;
          int r = p / TW, c = p % TW;
          int yo = 2 * (i0 + r) + pyp, xo = 2 * (j0 + c) + pxp;
          float v = fmaxf(acc[a][b][q], 0.f);
          outp[((long long)(n * COUT + co) * Ho + yo) * Wo + xo] = f2b(v);
        }
      }
  }
}

// ================= final 3x3 conv v2: LDS-tiled, 32x32 px tile, 3 couts =================
__global__ __launch_bounds__(256) void conv3x3_v2(
    const __hip_bfloat16* __restrict__ in, const float* __restrict__ w,
    const float* __restrict__ bias, float* __restrict__ out) {
  constexpr int H = 256, W = 256, CIN = 128;
  __shared__ float Wsh[3 * CIN * 9];
  __shared__ float T[4][34][35];

  const int tid = threadIdx.x;
  for (int u = tid; u < 3 * CIN * 9; u += 256) Wsh[u] = w[u];

  const int bx = blockIdx.x;
  const int n = bx >> 6;
  const int t8 = bx & 63;
  const int y0 = (t8 >> 3) * 32, x0 = (t8 & 7) * 32;
  const int ty = (tid >> 4) * 2;
  const int tx = (tid & 15) * 2;

  float acc[3][2][2];
#pragma unroll
  for (int co = 0; co < 3; ++co) {
    float b = bias[co];
    acc[co][0][0] = b; acc[co][0][1] = b; acc[co][1][0] = b; acc[co][1][1] = b;
  }

  for (int ch = 0; ch < CIN; ch += 4) {
    __syncthreads();
    for (int u = tid; u < 4 * 34 * 34; u += 256) {
      int ci = u / (34 * 34);
      int rem = u % (34 * 34);
      int r = rem / 34, c = rem % 34;
      int yy = y0 + r - 1, xx = x0 + c - 1;
      float v = 0.f;
      if ((unsigned)yy < (unsigned)H && (unsigned)xx < (unsigned)W)
        v = __bfloat162float(in[((long long)(n * CIN + ch + ci) * H + yy) * W + xx]);
      T[ci][r][c] = v;
    }
    __syncthreads();
#pragma unroll
    for (int ci = 0; ci < 4; ++ci) {
      float xv[4][4];
#pragma unroll
      for (int r = 0; r < 4; ++r)
#pragma unroll
        for (int c = 0; c < 4; ++c) xv[r][c] = T[ci][ty + r][tx + c];
#pragma unroll
      for (int co = 0; co < 3; ++co) {
        const float* __restrict__ wp = &Wsh[(co * CIN + ch + ci) * 9];
#pragma unroll
        for (int kh = 0; kh < 3; ++kh)
#pragma unroll
          for (int kw = 0; kw < 3; ++kw) {
            float wt = wp[kh * 3 + kw];
            acc[co][0][0] = fmaf(xv[kh][kw], wt, acc[co][0][0]);
            acc[co][0][1] = fmaf(xv[kh][kw + 1], wt, acc[co][0][1]);
            acc[co][1][0] = fmaf(xv[kh + 1][kw], wt, acc[co][1][0]);
            acc[co][1][1] = fmaf(xv[kh + 1][kw + 1], wt, acc[co][1][1]);
          }
      }
    }
  }
#pragma unroll
  for (int co = 0; co < 3; ++co)
#pragma unroll
    for (int dy = 0; dy < 2; ++dy) {
      long long ob = ((long long)(n * 3 + co) * H + y0 + ty + dy) * W + x0 + tx;
      *reinterpret_cast<float2*>(&out[ob]) = make_float2(acc[co][dy][0], acc[co][dy][1]);
    }
}

extern "C" void kernel_launch(void* const* d_in, const int* in_sizes, int n_in,
                              void* d_out, int out_size, void* d_ws, size_t ws_size,
                              hipStream_t stream) {
  const float* x   = (const float*)d_in[0];
  const float* ew0 = (const float*)d_in[1];  const float* eb0 = (const float*)d_in[2];
  const float* ew1 = (const float*)d_in[3];  const float* eb1 = (const float*)d_in[4];
  const float* ew2 = (const float*)d_in[5];  const float* eb2 = (const float*)d_in[6];
  const float* pw  = (const float*)d_in[7];  const float* pb  = (const float*)d_in[8];
  const float* dw0 = (const float*)d_in[9];  const float* db0 = (const float*)d_in[10];
  const float* dw1 = (const float*)d_in[11]; const float* db1 = (const float*)d_in[12];
  const float* dw2 = (const float*)d_in[13]; const float* db2 = (const float*)d_in[14];
  const float* ow  = (const float*)d_in[15]; const float* ob  = (const float*)d_in[16];
  const float* emb = (const float*)d_in[17];

  float* out   = (float*)d_out;
  float* recon = out;
  float* z     = out + 1572864;
  float* zq    = out + 3670016;
  float* resid = out + 5767168;
  float* codes = out + 14155776;

  char* ws = (char*)d_ws;
  dim3 blk(256);
  auto g = [](long long tot) { return dim3((unsigned)((tot + 255) / 256)); };

  // ---- workspace plan (~204.5 MB), same as rounds 13-18 ----
  const size_t OFF_S1IN  = 0ULL;
  const size_t OFF_S1OUT = 4734976ULL;
  const size_t OFF_WP1   = 40419328ULL;
  const size_t OFF_WP2   = 44613632ULL;
  const size_t OFF_P     = 67108864ULL;
  const size_t OFF_E2    = 134217728ULL;
  const size_t OFF_PWT   = 150994944ULL;
  const size_t OFF_DD2   = 0ULL;
  const size_t OFF_S2OUT = 134217728ULL;
  const size_t OFF_WP3   = 203440128ULL;
  const size_t OFF_EN    = 204488704ULL;
  const size_t WS_NEED   = 204505088ULL;

  if (ws_size < WS_NEED) return;  // prior rounds confirm ws_size is large enough

  float* e0  = (float*)(ws);
  float* p2  = (float*)(ws + OFF_P);
  float* e1  = (float*)(ws);
  float* p3  = (float*)(ws + OFF_P);
  float* e2  = (float*)(ws + OFF_E2);
  float* q1  = (float*)(ws + OFF_P);
  float* en  = (float*)(ws + OFF_EN);
  float* pwT = (float*)(ws + OFF_PWT);
  unsigned short* s1in  = (unsigned short*)(ws + OFF_S1IN);
  unsigned short* s1out = (unsigned short*)(ws + OFF_S1OUT);
  unsigned short* s2out = (unsigned short*)(ws + OFF_S2OUT);
  unsigned short* dd2   = (unsigned short*)(ws + OFF_DD2);
  unsigned short* wp1   = (unsigned short*)(ws + OFF_WP1);
  unsigned short* wp2   = (unsigned short*)(ws + OFF_WP2);
  unsigned short* wp3   = (unsigned short*)(ws + OFF_WP3);

  emb_norms<<<g(4096), blk, 0, stream>>>(emb, en);

  // encoder: L1 = verified v2 (single chunk); L2/L3 = v3 LDS-dbuf (1 barrier/chunk)
  conv_enc2<3, 128, 256, 3, 64, 1><<<dim3(512, 2, 1), blk, 0, stream>>>(x, ew0, eb0, e0);
  conv_enc3<128, 256, 128, 4, 64, 4><<<dim3(128, 4, 4), blk, 0, stream>>>(e0, ew1, eb1, p2);
  fuse_sum<4, true><<<dim3(4096), blk, 0, stream>>>(p2, e1, 8388608 / 4);
  conv_enc3<256, 512, 64, 4, 64, 4><<<dim3(32, 8, 4), blk, 0, stream>>>(e1, ew2, eb2, p3);
  fuse_sum<4, true><<<dim3(2048), blk, 0, stream>>>(p3, e2, 4194304 / 4);
  wtrans<<<g(512 * 256), blk, 0, stream>>>(pw, pwT);
  conv1x1_v2<4><<<dim3(64, 4, 4), blk, 0, stream>>>(e2, pwT, pb, q1);
  fuse_sum<4, false><<<dim3(1024), blk, 0, stream>>>(q1, z, 2097152 / 4);

  // residual quantization v6 (round-18, verified)
  rq_kernel6<<<dim3(256), dim3(512), 0, stream>>>(z, emb, en, zq, resid, codes);

  // decoder prep
  hipMemsetAsync(ws + OFF_S1IN, 0, 4734976ULL, stream);
  hipMemsetAsync(ws + OFF_S1OUT, 0, 35684352ULL, stream);
  hipMemsetAsync(ws + OFF_S2OUT, 0, 69222400ULL, stream);
  to_nhwc_s1<<<dim3(2048), blk, 0, stream>>>(zq, s1in);
  wprep_k<<<g(16LL * 256 * 512), blk, 0, stream>>>(dw0, wp1, 256, 512);
  wprep_k<<<g(16LL * 512 * 256), blk, 0, stream>>>(dw1, wp2, 512, 256);
  wprep_k<<<g(16LL * 256 * 128), blk, 0, stream>>>(dw2, wp3, 256, 128);

  // decoder MFMA stages
  convt2<256, 512, 8, 32, 32, 32, false>
      <<<dim3(32, 8, 4), dim3(256), 0, stream>>>(s1in, wp1, db0, s1out);
  convt2<512, 256, 4, 64, 64, 64, false>
      <<<dim3(128, 4, 4), dim3(256), 0, stream>>>(s1out, wp2, db1, s2out);
  convt2<256, 128, 4, 64, 128, 128, true>
      <<<dim3(512, 2, 4), dim3(256), 0, stream>>>(s2out, wp3, db2, dd2);

  // final 3x3 conv: LDS-tiled
  conv3x3_v2<<<dim3(512), blk, 0, stream>>>((const __hip_bfloat16*)dd2, ow, ob, recon);
}

// Round 20
// 2654.669 us; speedup vs baseline: 1.2836x; 1.2836x over previous
//
#include <hip/hip_runtime.h>
#include <hip/hip_bf16.h>
#include <cstdint>

#define BATCH 8
#define LATC 256
#define NCODE 1024
#define NLVL 4

typedef __attribute__((ext_vector_type(8))) short bf16x8v;
typedef __attribute__((ext_vector_type(4))) float f32x4v;

__device__ __forceinline__ unsigned short f2b(float f) {
  __hip_bfloat16 h = __float2bfloat16(f);
  return *reinterpret_cast<unsigned short*>(&h);
}

// async global->LDS 16B: LDS base = readfirstlane(lane0 offset), HW writes base + lane*16
__device__ __forceinline__ void gl_lds16(const void* gptr, unsigned lds_byte_off) {
  unsigned m0v = __builtin_amdgcn_readfirstlane(lds_byte_off);
  asm volatile("s_mov_b32 m0, %0\n"
               "global_load_lds_dwordx4 %1, off\n" ::"s"(m0v), "v"(gptr)
               : "memory");
}

// ================= encoder conv k4 s2 p1 v2: 8px x 8co per thread (round-14, verified) ========
template <int CIN, int COUT, int HIN, int CI_CHUNK, int CO_TILE, int CI_SPLIT>
__global__ __launch_bounds__(256) void conv_enc2(
    const float* __restrict__ in, const float* __restrict__ w,
    const float* __restrict__ bias, float* __restrict__ out) {
  constexpr int WIN = HIN;
  constexpr int HOUT = HIN / 2, WOUT = WIN / 2;
  constexpr int PT1 = HOUT / 16;
  constexpr int NEL = CI_CHUNK * 34 * 34;
  constexpr int WUNITS = CI_CHUNK * CO_TILE * 4;
  constexpr int CIPS = CIN / CI_SPLIT;

  __shared__ float T[CI_CHUNK][34][40];
  __shared__ float4 Wsh[CI_CHUNK][CO_TILE][4];

  const int tid = threadIdx.x;
  const int lane = tid & 63;
  const int wv = __builtin_amdgcn_readfirstlane(tid >> 6);
  const int cog = lane >> 5;
  const int pxi = lane & 31;
  const int m = pxi >> 2;
  const int ox4 = pxi & 3;
  const int co_loc0 = (wv * 2 + cog) * 8;

  const int bx = blockIdx.x;
  const int n = bx / (PT1 * PT1);
  const int pt = bx % (PT1 * PT1);
  const int oh0 = (pt / PT1) * 16, ow0 = (pt % PT1) * 16;
  const int hbase = 2 * oh0 - 1, wbase = 2 * ow0 - 1;
  const int co_blk = blockIdx.y * CO_TILE;
  const int split = (CI_SPLIT > 1) ? blockIdx.z : 0;
  const int ci_base = split * CIPS;

  float acc[2][4][2][4];
#pragma unroll
  for (int cl = 0; cl < 2; ++cl)
#pragma unroll
    for (int j = 0; j < 4; ++j) {
      float b = (CI_SPLIT == 1 || split == 0) ? bias[co_blk + co_loc0 + cl * 4 + j] : 0.f;
#pragma unroll
      for (int dy = 0; dy < 2; ++dy)
#pragma unroll
        for (int dx = 0; dx < 4; ++dx) acc[cl][j][dy][dx] = b;
    }

  for (int ch = ci_base; ch < ci_base + CIPS; ch += CI_CHUNK) {
    for (int u = tid; u < NEL; u += 256) {
      int cir = u / 1156;
      int rem = u - cir * 1156;
      int r = rem / 34, c = rem - r * 34;
      int hi = hbase + r, wi = wbase + c;
      float v = 0.f;
      if ((unsigned)hi < (unsigned)HIN && (unsigned)wi < (unsigned)WIN)
        v = in[((long long)(n * CIN + ch + cir) * HIN + hi) * WIN + wi];
      T[cir][r][(((r >> 2) & 1) << 2) + c] = v;
    }
    for (int u = tid; u < WUNITS; u += 256) {
      int k4 = u & 3;
      int rem = u >> 2;
      int co = rem % CO_TILE, ci = rem / CO_TILE;
      Wsh[ci][co][k4] =
          *(const float4*)&w[((long long)(co_blk + co) * CIN + ch + ci) * 16 + k4 * 4];
    }
    __syncthreads();
#pragma unroll
    for (int cir = 0; cir < CI_CHUNK; ++cir) {
      float xv[6][10];
#pragma unroll
      for (int roff = 0; roff < 6; ++roff) {
        int row = 4 * m + roff;
        const float* base = &T[cir][row][(((row >> 2) & 1) << 2) + 8 * ox4];
        float4 qa = *(const float4*)base;
        float4 qb = *(const float4*)(base + 4);
        float4 qc = *(const float4*)(base + 8);
        xv[roff][0] = qa.x; xv[roff][1] = qa.y; xv[roff][2] = qa.z; xv[roff][3] = qa.w;
        xv[roff][4] = qb.x; xv[roff][5] = qb.y; xv[roff][6] = qb.z; xv[roff][7] = qb.w;
        xv[roff][8] = qc.x; xv[roff][9] = qc.y;
      }
#pragma unroll
      for (int cl = 0; cl < 2; ++cl)
#pragma unroll
        for (int j = 0; j < 4; ++j) {
          int co_l = co_loc0 + cl * 4 + j;
#pragma unroll
          for (int kh = 0; kh < 4; ++kh) {
            float4 wq = Wsh[cir][co_l][kh];
            float wt0 = wq.x, wt1 = wq.y, wt2 = wq.z, wt3 = wq.w;
#pragma unroll
            for (int dy = 0; dy < 2; ++dy) {
              int r = 2 * dy + kh;
#pragma unroll
              for (int dx = 0; dx < 4; ++dx) {
                acc[cl][j][dy][dx] = fmaf(xv[r][2 * dx + 0], wt0, acc[cl][j][dy][dx]);
                acc[cl][j][dy][dx] = fmaf(xv[r][2 * dx + 1], wt1, acc[cl][j][dy][dx]);
                acc[cl][j][dy][dx] = fmaf(xv[r][2 * dx + 2], wt2, acc[cl][j][dy][dx]);
                acc[cl][j][dy][dx] = fmaf(xv[r][2 * dx + 3], wt3, acc[cl][j][dy][dx]);
              }
            }
          }
        }
    }
    __syncthreads();
  }
  const long long psz = (long long)BATCH * COUT * HOUT * WOUT;
  float* __restrict__ ob_ptr = out + (CI_SPLIT > 1 ? (long long)split * psz : 0LL);
#pragma unroll
  for (int cl = 0; cl < 2; ++cl)
#pragma unroll
    for (int j = 0; j < 4; ++j) {
      int co = co_blk + co_loc0 + cl * 4 + j;
#pragma unroll
      for (int dy = 0; dy < 2; ++dy) {
        int oh = oh0 + 2 * m + dy, ow = ow0 + 4 * ox4;
        float4 v;
#pragma unroll
        for (int dx = 0; dx < 4; ++dx) {
          float t = acc[cl][j][dy][dx];
          if (CI_SPLIT == 1) t = fmaxf(t, 0.f);
          ((float*)&v)[dx] = t;
        }
        *reinterpret_cast<float4*>(
            &ob_ptr[((long long)(n * COUT + co) * HOUT + oh) * WOUT + ow]) = v;
      }
    }
}

// ---------------- fuse: out = (relu?) sum of S partials ----------------
template <int S, bool RELU>
__global__ __launch_bounds__(256) void fuse_sum(const float* __restrict__ p,
                                                float* __restrict__ out, long long n4) {
  long long i = (long long)blockIdx.x * 256 + threadIdx.x;
  long long stride = (long long)gridDim.x * 256;
  long long N = n4 * 4;
  for (; i < n4; i += stride) {
    float4 a = *(const float4*)&p[i * 4];
#pragma unroll
    for (int s = 1; s < S; ++s) {
      float4 b = *(const float4*)&p[(long long)s * N + i * 4];
      a.x += b.x; a.y += b.y; a.z += b.z; a.w += b.w;
    }
    if (RELU) {
      a.x = fmaxf(a.x, 0.f); a.y = fmaxf(a.y, 0.f);
      a.z = fmaxf(a.z, 0.f); a.w = fmaxf(a.w, 0.f);
    }
    *(float4*)&out[i * 4] = a;
  }
}

// ---------------- weight transpose for 1x1 conv ----------------
__global__ __launch_bounds__(256) void wtrans(const float* __restrict__ pw,
                                              float* __restrict__ pwT) {
  int gid = blockIdx.x * 256 + threadIdx.x;
  if (gid >= 512 * 256) return;
  int ci = gid >> 8, co = gid & 255;
  pwT[gid] = pw[co * 512 + ci];
}

// ---------------- 1x1 conv as GEMM, ci-split (z) ----------------
template <int CI_SPLIT>
__global__ __launch_bounds__(256) void conv1x1_v2(
    const float* __restrict__ in, const float* __restrict__ pwT,
    const float* __restrict__ bias, float* __restrict__ out) {
  constexpr int CIPS = 512 / CI_SPLIT;
  __shared__ float Tx[16][128];
  const int tid = threadIdx.x;
  const int lane = tid & 63;
  const int wv = __builtin_amdgcn_readfirstlane(tid >> 6);
  const int p0 = lane * 2;
  const int bx = blockIdx.x;
  const int n = bx >> 3, pxb = bx & 7;
  const int px_base = pxb * 128;
  const int co_base = blockIdx.y * 64 + wv * 16;
  const int split = (CI_SPLIT > 1) ? blockIdx.z : 0;
  const int ci0 = split * CIPS;

  float acc[4][4][2];
#pragma unroll
  for (int cl = 0; cl < 4; ++cl)
#pragma unroll
    for (int j = 0; j < 4; ++j) {
      float b = (CI_SPLIT == 1 || split == 0) ? bias[co_base + cl * 4 + j] : 0.f;
      acc[cl][j][0] = b; acc[cl][j][1] = b;
    }

  for (int ch = ci0; ch < ci0 + CIPS; ch += 16) {
    for (int u = tid; u < 2048; u += 256) {
      int cir = u >> 7, p = u & 127;
      Tx[cir][p] = in[(long long)(n * 512 + ch + cir) * 1024 + px_base + p];
    }
    __syncthreads();
#pragma unroll
    for (int cir = 0; cir < 16; ++cir) {
      float2 xv = *reinterpret_cast<const float2*>(&Tx[cir][p0]);
#pragma unroll
      for (int cl = 0; cl < 4; ++cl) {
        const float* __restrict__ wp = pwT + (ch + cir) * 256 + co_base + cl * 4;
#pragma unroll
        for (int j = 0; j < 4; ++j) {
          float wt = wp[j];
          acc[cl][j][0] = fmaf(xv.x, wt, acc[cl][j][0]);
          acc[cl][j][1] = fmaf(xv.y, wt, acc[cl][j][1]);
        }
      }
    }
    __syncthreads();
  }
  const long long psz = (long long)BATCH * 256 * 1024;
  float* __restrict__ ob = out + (CI_SPLIT > 1 ? (long long)split * psz : 0LL);
#pragma unroll
  for (int cl = 0; cl < 4; ++cl)
#pragma unroll
    for (int j = 0; j < 4; ++j) {
      int co = co_base + cl * 4 + j;
      *reinterpret_cast<float2*>(&ob[(long long)(n * 256 + co) * 1024 + px_base + p0]) =
          make_float2(acc[cl][j][0], acc[cl][j][1]);
    }
}

// ---------------- per-code squared norms ----------------
__global__ __launch_bounds__(256) void emb_norms(
    const float* __restrict__ emb, float* __restrict__ en) {
  int k = blockIdx.x * blockDim.x + threadIdx.x;
  if (k >= NLVL * NCODE) return;
  const float* __restrict__ e = emb + (long long)k * LATC;
  float s = 0.f;
  for (int c = 0; c < LATC; ++c) s = fmaf(e[c], e[c], s);
  en[k] = s;
}

// ================= residual quantization v6: 512 threads (2 waves/SIMD), 64-code tiles ========
#define RQ_P 32
#define RQ_CT 64
#define RQ_RS 260

__global__ __launch_bounds__(512) void rq_kernel6(
    const float* __restrict__ z, const float* __restrict__ emb,
    const float* __restrict__ en, float* __restrict__ zq_out,
    float* __restrict__ resid_out, float* __restrict__ codes_out) {
  __shared__ float e_sh[RQ_CT * RQ_RS];
  __shared__ float r_sh[RQ_P * RQ_RS];
  __shared__ float sum_sh[RQ_P];
  __shared__ float red_d[2][RQ_P];
  __shared__ int red_i[2][RQ_P];
  __shared__ int code_sh[RQ_P];
  const int tid = threadIdx.x;
  const int blk = blockIdx.x;
  const int n = (blk * RQ_P) >> 10;
  const int hw0 = (blk * RQ_P) & 1023;
  const long long zb = ((long long)n * LATC) * 1024 + hw0;

  for (int it = 0; it < 16; ++it) {
    int u = it * 512 + tid;
    int c = u >> 5, pix = u & 31;
    float v = z[zb + (long long)c * 1024 + pix];
    r_sh[pix * RQ_RS + c] = v;
    resid_out[((long long)n * LATC + c) * 1024 + hw0 + pix] = v;
  }
  __syncthreads();

  const int code_l = tid & 31;
  const int pixoff = (tid >> 5) & 7;
  const int half = tid >> 8;
  const int upix = tid >> 4;
  const int ucg = tid & 15;

  for (int l = 0; l < NLVL; ++l) {
    {
      float s = 0.f;
#pragma unroll
      for (int it = 0; it < 4; ++it) {
        int c4 = ucg + it * 16;
        float4 r4 = *(const float4*)&r_sh[upix * RQ_RS + c4 * 4];
        s += r4.x * r4.x + r4.y * r4.y + r4.z * r4.z + r4.w * r4.w;
      }
      s += __shfl_xor(s, 1); s += __shfl_xor(s, 2);
      s += __shfl_xor(s, 4); s += __shfl_xor(s, 8);
      if (ucg == 0) sum_sh[upix] = s;
    }
    __syncthreads();
    const float* __restrict__ E = emb + (long long)l * NCODE * LATC;
    const float* __restrict__ enl = en + l * NCODE;
    float best[4]; int bidx[4];
#pragma unroll
    for (int g = 0; g < 4; ++g) { best[g] = 3.4e38f; bidx[g] = 0; }
    for (int tile = 0; tile < NCODE / RQ_CT; ++tile) {
      const float* __restrict__ Et = E + (long long)tile * RQ_CT * LATC;
      for (int it = 0; it < 32; ++it) {
        int u = it * 512 + tid;
        int cc = u >> 8, ch = u & 255;
        e_sh[cc * RQ_RS + ch] = Et[cc * LATC + ch];
      }
      __syncthreads();
      const int erow = half * 32 + code_l;
      float acc[4] = {0.f, 0.f, 0.f, 0.f};
      for (int c4 = 0; c4 < 64; ++c4) {
        float4 e4 = *(const float4*)&e_sh[erow * RQ_RS + c4 * 4];
#pragma unroll
        for (int g = 0; g < 4; ++g) {
          float4 r4 = *(const float4*)&r_sh[(g * 8 + pixoff) * RQ_RS + c4 * 4];
          acc[g] = fmaf(r4.x, e4.x, acc[g]);
          acc[g] = fmaf(r4.y, e4.y, acc[g]);
          acc[g] = fmaf(r4.z, e4.z, acc[g]);
          acc[g] = fmaf(r4.w, e4.w, acc[g]);
        }
      }
      int code = tile * RQ_CT + erow;
      float ek2 = enl[code];
#pragma unroll
      for (int g = 0; g < 4; ++g) {
        float d2 = (sum_sh[g * 8 + pixoff] - 2.f * acc[g]) + ek2;
        if (d2 < best[g]) { best[g] = d2; bidx[g] = code; }
      }
      __syncthreads();
    }
#pragma unroll
    for (int g = 0; g < 4; ++g) {
      float bd = best[g]; int bi = bidx[g];
#pragma unroll
      for (int m = 1; m < 32; m <<= 1) {
        float od = __shfl_xor(bd, m);
        int oi = __shfl_xor(bi, m);
        if (od < bd || (od == bd && oi < bi)) { bd = od; bi = oi; }
      }
      if (code_l == 0) {
        int pix = g * 8 + pixoff;
        red_d[half][pix] = bd; red_i[half][pix] = bi;
      }
    }
    __syncthreads();
    if (tid < RQ_P) {
      float d = red_d[0][tid]; int ix = red_i[0][tid];
      float od = red_d[1][tid]; int oi = red_i[1][tid];
      if (od < d || (od == d && oi < ix)) { d = od; ix = oi; }
      code_sh[tid] = ix;
      codes_out[(long long)(l * BATCH + n) * 1024 + hw0 + tid] = (float)ix;
    }
    __syncthreads();
    {
      int sel = code_sh[upix];
      const float* __restrict__ esel = E + (long long)sel * LATC;
#pragma unroll
      for (int it = 0; it < 4; ++it) {
        int c4 = ucg + it * 16;
        float4 r4 = *(const float4*)&r_sh[upix * RQ_RS + c4 * 4];
        float4 e4 = *(const float4*)&esel[c4 * 4];
        r4.x -= e4.x; r4.y -= e4.y; r4.z -= e4.z; r4.w -= e4.w;
        *(float4*)&r_sh[upix * RQ_RS + c4 * 4] = r4;
        if (l < NLVL - 1) {
          long long rb = ((long long)((l + 1) * BATCH + n) * LATC + c4 * 4) * 1024 + hw0 + upix;
          resid_out[rb] = r4.x;
          resid_out[rb + 1024] = r4.y;
          resid_out[rb + 2048] = r4.z;
          resid_out[rb + 3072] = r4.w;
        }
      }
    }
    __syncthreads();
  }
  for (int it = 0; it < 16; ++it) {
    int u = it * 512 + tid;
    int c = u >> 5, pix = u & 31;
    float zv = z[zb + (long long)c * 1024 + pix];
    zq_out[zb + (long long)c * 1024 + pix] = zv - r_sh[pix * RQ_RS + c];
  }
}

// ---------------- zq (NCHW f32) -> padded NHWC bf16 [8][34][34][256] ----------------
__global__ __launch_bounds__(256) void to_nhwc_s1(const float* __restrict__ zq,
                                                  unsigned short* __restrict__ o) {
  __shared__ float tsh[32][33];
  int bx = blockIdx.x;
  int ct = bx & 7, y = (bx >> 3) & 31, n = bx >> 8;
  int tid = threadIdx.x;
  int x = tid & 31, cl = tid >> 5;
#pragma unroll
  for (int it = 0; it < 4; ++it) {
    int ci = it * 8 + cl;
    tsh[ci][x] = zq[((long long)(n * 256 + ct * 32 + ci) * 32 + y) * 32 + x];
  }
  __syncthreads();
  int ci = tid & 31, xg = tid >> 5;
#pragma unroll
  for (int it = 0; it < 4; ++it) {
    int xw = it * 8 + xg;
    o[(((long long)n * 34 + y + 1) * 34 + xw + 1) * 256 + ct * 32 + ci] = f2b(tsh[ci][xw]);
  }
}

// ---------------- weight prep: HWIO f32 -> [4ph][CIN/32][4tap][COUT][32] bf16 ----------------
__global__ __launch_bounds__(256) void wprep_k(const float* __restrict__ w,
                                               unsigned short* __restrict__ o,
                                               int CINc, int COUTc) {
  long long total = 16LL * CINc * COUTc;
  long long gid = (long long)blockIdx.x * 256 + threadIdx.x;
  if (gid >= total) return;
  int ci32 = (int)(gid & 31); long long t = gid >> 5;
  int co = (int)(t % COUTc); t /= COUTc;
  int tap = (int)(t & 3); t >>= 2;
  int nch = CINc / 32;
  int ch = (int)(t % nch); int phase = (int)(t / nch);
  int py = phase >> 1, px = phase & 1;
  int ky = py + 2 * (tap >> 1), kx = px + 2 * (tap & 1);
  int ci = ch * 32 + ci32;
  float v = w[(((long long)ky * 4 + kx) * CINc + ci) * COUTc + co];
  o[gid] = f2b(v);
}

// ================= transposed conv k4 s2 MFMA v2: plane-layout LDS ================
template <int CIN, int COUT, int TH, int TW, int Hi, int Wi, bool OUT_NCHW>
__global__ __launch_bounds__(256) void convt2(
    const unsigned short* __restrict__ xin, const unsigned short* __restrict__ wprep,
    const float* __restrict__ bias, unsigned short* __restrict__ outp) {
  constexpr int TWP = TW + 2, ROWS = TH + 2;
  constexpr int Hp = Hi + 2, Wp = Wi + 2;
  constexpr int NCH = CIN / 32;
  constexpr int XUNITS = ROWS * TWP;
  constexpr int XPAD = ((XUNITS + 255) / 256) * 256;
  constexpr int WBASE = 4 * XPAD;
  __shared__ unsigned short lds[(4 * XPAD + 4 * 256) * 8];

  const int tid = threadIdx.x;
  const int wv = tid >> 6, lane = tid & 63;
  const int l15 = lane & 15, seg = lane >> 4;

  constexpr int SW = Wi / TW, SH = Hi / TH;
  const int bx = blockIdx.x;
  const int n = bx / (SH * SW);
  const int srem = bx % (SH * SW);
  const int i0 = (srem / SW) * TH, j0 = (srem % SW) * TW;
  const int cob0 = blockIdx.y * 64;
  const int phase = blockIdx.z;
  const int pyp = phase >> 1, pxp = phase & 1;

  const unsigned short* xsrc = xin + (long long)n * Hp * Wp * CIN;

  f32x4v acc[4][4];
  if (!OUT_NCHW) {
#pragma unroll
    for (int b = 0; b < 4; ++b) {
      float bv = bias[cob0 + b * 16 + l15];
      f32x4v v = {bv, bv, bv, bv};
#pragma unroll
      for (int a = 0; a < 4; ++a) acc[a][b] = v;
    }
  } else {
#pragma unroll
    for (int a = 0; a < 4; ++a) {
      f32x4v v;
#pragma unroll
      for (int q = 0; q < 4; ++q) v[q] = bias[cob0 + a * 16 + seg * 4 + q];
#pragma unroll
      for (int b = 0; b < 4; ++b) acc[a][b] = v;
    }
  }

  for (int ch = 0; ch < NCH; ++ch) {
    __syncthreads();
#pragma unroll
    for (int sg = 0; sg < 4; ++sg) {
#pragma unroll
      for (int it = 0; it < XPAD / 256; ++it) {
        int u = it * 256 + tid;
        int us = u < XUNITS ? u : XUNITS - 1;
        int row = us / TWP, col = us % TWP;
        const unsigned short* g =
            xsrc + ((long long)(i0 + row) * Wp + (j0 + col)) * CIN + ch * 32 + sg * 8;
        gl_lds16(g, (unsigned)(unsigned long long)(const void*)&lds[(sg * XPAD + u) * 8]);
      }
    }
    {
      const unsigned short* wb = wprep + ((long long)phase * NCH + ch) * 4 * COUT * 32;
      int tap = tid >> 6, co = tid & 63;
#pragma unroll
      for (int sg = 0; sg < 4; ++sg) {
        const unsigned short* g = wb + ((long long)tap * COUT + cob0 + co) * 32 + sg * 8;
        gl_lds16(g, (unsigned)(unsigned long long)(const void*)&lds[(WBASE + sg * 256 + tid) * 8]);
      }
    }
    asm volatile("s_waitcnt vmcnt(0)" ::: "memory");
    __syncthreads();
#pragma unroll
    for (int t = 0; t < 4; ++t) {
      int oy = (t >> 1) - 1 + pyp, ox = (t & 1) - 1 + pxp;
      bf16x8v xf[4], wf[4];
#pragma unroll
      for (int i = 0; i < 4; ++i) {
        int p = wv * 64 + i * 16 + l15;
        int r = p / TW, c = p % TW;
        int xrow = r + oy + 1, xcol = c + ox + 1;
        xf[i] = *(const bf16x8v*)&lds[(seg * XPAD + xrow * TWP + xcol) * 8];
        wf[i] = *(const bf16x8v*)&lds[(WBASE + seg * 256 + t * 64 + i * 16 + l15) * 8];
      }
#pragma unroll
      for (int a = 0; a < 4; ++a)
#pragma unroll
        for (int b = 0; b < 4; ++b) {
          if (OUT_NCHW)
            acc[a][b] = __builtin_amdgcn_mfma_f32_16x16x32_bf16(wf[a], xf[b], acc[a][b], 0, 0, 0);
          else
            acc[a][b] = __builtin_amdgcn_mfma_f32_16x16x32_bf16(xf[a], wf[b], acc[a][b], 0, 0, 0);
        }
    }
  }

  if (!OUT_NCHW) {
    constexpr int Wpo = 2 * Wi + 2;
    long long ob_n = (long long)n * (2 * Hi + 2) * Wpo * COUT;
#pragma unroll
    for (int a = 0; a < 4; ++a)
#pragma unroll
      for (int q = 0; q < 4; ++q) {
        int p = wv * 64 + a * 16 + seg * 4 + q;
        int r = p / TW, c = p % TW;
        int yo = 2 * (i0 + r) + pyp + 1, xo = 2 * (j0 + c) + pxp + 1;
        long long ob = ob_n + ((long long)yo * Wpo + xo) * COUT + cob0;
#pragma unroll
        for (int b = 0; b < 4; ++b) {
          float v = fmaxf(acc[a][b][q], 0.f);
          outp[ob + b * 16 + l15] = f2b(v);
        }
      }
  } else {
    constexpr int Ho = 2 * Hi, Wo = 2 * Wi;
#pragma unroll
    for (int a = 0; a < 4; ++a)
#pragma unroll
      for (int q = 0; q < 4; ++q) {
        int co = cob0 + a * 16 + seg * 4 + q;
#pragma unroll
        for (int b = 0; b < 4; ++b) {
          int p = wv * 64 + b * 16 + l15;
          int r = p / TW, c = p % TW;
          int yo = 2 * (i0 + r) + pyp, xo = 2 * (j0 + c) + pxp;
          float v = fmaxf(acc[a][b][q], 0.f);
          outp[((long long)(n * COUT + co) * Ho + yo) * Wo + xo] = f2b(v);
        }
      }
  }
}

// ================= final 3x3 conv v2: LDS-tiled, 32x32 px tile, 3 couts =================
__global__ __launch_bounds__(256) void conv3x3_v2(
    const __hip_bfloat16* __restrict__ in, const float* __restrict__ w,
    const float* __restrict__ bias, float* __restrict__ out) {
  constexpr int H = 256, W = 256, CIN = 128;
  __shared__ float Wsh[3 * CIN * 9];
  __shared__ float T[4][34][35];

  const int tid = threadIdx.x;
  for (int u = tid; u < 3 * CIN * 9; u += 256) Wsh[u] = w[u];

  const int bx = blockIdx.x;
  const int n = bx >> 6;
  const int t8 = bx & 63;
  const int y0 = (t8 >> 3) * 32, x0 = (t8 & 7) * 32;
  const int ty = (tid >> 4) * 2;
  const int tx = (tid & 15) * 2;

  float acc[3][2][2];
#pragma unroll
  for (int co = 0; co < 3; ++co) {
    float b = bias[co];
    acc[co][0][0] = b; acc[co][0][1] = b; acc[co][1][0] = b; acc[co][1][1] = b;
  }

  for (int ch = 0; ch < CIN; ch += 4) {
    __syncthreads();
    for (int u = tid; u < 4 * 34 * 34; u += 256) {
      int ci = u / (34 * 34);
      int rem = u % (34 * 34);
      int r = rem / 34, c = rem % 34;
      int yy = y0 + r - 1, xx = x0 + c - 1;
      float v = 0.f;
      if ((unsigned)yy < (unsigned)H && (unsigned)xx < (unsigned)W)
        v = __bfloat162float(in[((long long)(n * CIN + ch + ci) * H + yy) * W + xx]);
      T[ci][r][c] = v;
    }
    __syncthreads();
#pragma unroll
    for (int ci = 0; ci < 4; ++ci) {
      float xv[4][4];
#pragma unroll
      for (int r = 0; r < 4; ++r)
#pragma unroll
        for (int c = 0; c < 4; ++c) xv[r][c] = T[ci][ty + r][tx + c];
#pragma unroll
      for (int co = 0; co < 3; ++co) {
        const float* __restrict__ wp = &Wsh[(co * CIN + ch + ci) * 9];
#pragma unroll
        for (int kh = 0; kh < 3; ++kh)
#pragma unroll
          for (int kw = 0; kw < 3; ++kw) {
            float wt = wp[kh * 3 + kw];
            acc[co][0][0] = fmaf(xv[kh][kw], wt, acc[co][0][0]);
            acc[co][0][1] = fmaf(xv[kh][kw + 1], wt, acc[co][0][1]);
            acc[co][1][0] = fmaf(xv[kh + 1][kw], wt, acc[co][1][0]);
            acc[co][1][1] = fmaf(xv[kh + 1][kw + 1], wt, acc[co][1][1]);
          }
      }
    }
  }
#pragma unroll
  for (int co = 0; co < 3; ++co)
#pragma unroll
    for (int dy = 0; dy < 2; ++dy) {
      long long ob = ((long long)(n * 3 + co) * H + y0 + ty + dy) * W + x0 + tx;
      *reinterpret_cast<float2*>(&out[ob]) = make_float2(acc[co][dy][0], acc[co][dy][1]);
    }
}

extern "C" void kernel_launch(void* const* d_in, const int* in_sizes, int n_in,
                              void* d_out, int out_size, void* d_ws, size_t ws_size,
                              hipStream_t stream) {
  const float* x   = (const float*)d_in[0];
  const float* ew0 = (const float*)d_in[1];  const float* eb0 = (const float*)d_in[2];
  const float* ew1 = (const float*)d_in[3];  const float* eb1 = (const float*)d_in[4];
  const float* ew2 = (const float*)d_in[5];  const float* eb2 = (const float*)d_in[6];
  const float* pw  = (const float*)d_in[7];  const float* pb  = (const float*)d_in[8];
  const float* dw0 = (const float*)d_in[9];  const float* db0 = (const float*)d_in[10];
  const float* dw1 = (const float*)d_in[11]; const float* db1 = (const float*)d_in[12];
  const float* dw2 = (const float*)d_in[13]; const float* db2 = (const float*)d_in[14];
  const float* ow  = (const float*)d_in[15]; const float* ob  = (const float*)d_in[16];
  const float* emb = (const float*)d_in[17];

  float* out   = (float*)d_out;
  float* recon = out;
  float* z     = out + 1572864;
  float* zq    = out + 3670016;
  float* resid = out + 5767168;
  float* codes = out + 14155776;

  char* ws = (char*)d_ws;
  dim3 blk(256);
  auto g = [](long long tot) { return dim3((unsigned)((tot + 255) / 256)); };

  // ---- workspace plan (~204.5 MB), same as rounds 13-18 ----
  const size_t OFF_S1IN  = 0ULL;
  const size_t OFF_S1OUT = 4734976ULL;
  const size_t OFF_WP1   = 40419328ULL;
  const size_t OFF_WP2   = 44613632ULL;
  const size_t OFF_P     = 67108864ULL;
  const size_t OFF_E2    = 134217728ULL;
  const size_t OFF_PWT   = 150994944ULL;
  const size_t OFF_DD2   = 0ULL;
  const size_t OFF_S2OUT = 134217728ULL;
  const size_t OFF_WP3   = 203440128ULL;
  const size_t OFF_EN    = 204488704ULL;
  const size_t WS_NEED   = 204505088ULL;

  if (ws_size < WS_NEED) return;  // prior rounds confirm ws_size is large enough

  float* e0  = (float*)(ws);
  float* p2  = (float*)(ws + OFF_P);
  float* e1  = (float*)(ws);
  float* p3  = (float*)(ws + OFF_P);
  float* e2  = (float*)(ws + OFF_E2);
  float* q1  = (float*)(ws + OFF_P);
  float* en  = (float*)(ws + OFF_EN);
  float* pwT = (float*)(ws + OFF_PWT);
  unsigned short* s1in  = (unsigned short*)(ws + OFF_S1IN);
  unsigned short* s1out = (unsigned short*)(ws + OFF_S1OUT);
  unsigned short* s2out = (unsigned short*)(ws + OFF_S2OUT);
  unsigned short* dd2   = (unsigned short*)(ws + OFF_DD2);
  unsigned short* wp1   = (unsigned short*)(ws + OFF_WP1);
  unsigned short* wp2   = (unsigned short*)(ws + OFF_WP2);
  unsigned short* wp3   = (unsigned short*)(ws + OFF_WP3);

  emb_norms<<<g(4096), blk, 0, stream>>>(emb, en);

  // encoder v2 (round-14, verified)
  conv_enc2<3, 128, 256, 3, 64, 1><<<dim3(512, 2, 1), blk, 0, stream>>>(x, ew0, eb0, e0);
  conv_enc2<128, 256, 128, 4, 64, 4><<<dim3(128, 4, 4), blk, 0, stream>>>(e0, ew1, eb1, p2);
  fuse_sum<4, true><<<dim3(4096), blk, 0, stream>>>(p2, e1, 8388608 / 4);
  conv_enc2<256, 512, 64, 4, 64, 4><<<dim3(32, 8, 4), blk, 0, stream>>>(e1, ew2, eb2, p3);
  fuse_sum<4, true><<<dim3(2048), blk, 0, stream>>>(p3, e2, 4194304 / 4);
  wtrans<<<g(512 * 256), blk, 0, stream>>>(pw, pwT);
  conv1x1_v2<4><<<dim3(64, 4, 4), blk, 0, stream>>>(e2, pwT, pb, q1);
  fuse_sum<4, false><<<dim3(1024), blk, 0, stream>>>(q1, z, 2097152 / 4);

  // residual quantization v6: 512 threads, 2 waves/SIMD
  rq_kernel6<<<dim3(256), dim3(512), 0, stream>>>(z, emb, en, zq, resid, codes);

  // decoder prep
  hipMemsetAsync(ws + OFF_S1IN, 0, 4734976ULL, stream);
  hipMemsetAsync(ws + OFF_S1OUT, 0, 35684352ULL, stream);
  hipMemsetAsync(ws + OFF_S2OUT, 0, 69222400ULL, stream);
  to_nhwc_s1<<<dim3(2048), blk, 0, stream>>>(zq, s1in);
  wprep_k<<<g(16LL * 256 * 512), blk, 0, stream>>>(dw0, wp1, 256, 512);
  wprep_k<<<g(16LL * 512 * 256), blk, 0, stream>>>(dw1, wp2, 512, 256);
  wprep_k<<<g(16LL * 256 * 128), blk, 0, stream>>>(dw2, wp3, 256, 128);

  // decoder MFMA stages
  convt2<256, 512, 8, 32, 32, 32, false>
      <<<dim3(32, 8, 4), dim3(256), 0, stream>>>(s1in, wp1, db0, s1out);
  convt2<512, 256, 4, 64, 64, 64, false>
      <<<dim3(128, 4, 4), dim3(256), 0, stream>>>(s1out, wp2, db1, s2out);
  convt2<256, 128, 4, 64, 128, 128, true>
      <<<dim3(512, 2, 4), dim3(256), 0, stream>>>(s2out, wp3, db2, dd2);

  // final 3x3 conv: LDS-tiled
  conv3x3_v2<<<dim3(512), blk, 0, stream>>>((const __hip_bfloat16*)dd2, ow, ob, recon);
}